// Round 3
// baseline (1025.415 us; speedup 1.0000x reference)
//
#include <hip/hip_runtime.h>

#define N_NODES 100000
#define N_EDGES 3200000
#define N_GRAPHS 64
#define F 16

#define NBUCK 256
#define CPB 391                 // cols per bucket: 256*391 = 100096 >= N_NODES
#define BIN_CAP 32
#define G_FILL 64
#define FILL_T 1024
#define ROUNDS ((N_EDGES + G_FILL * FILL_T - 1) / (G_FILL * FILL_T))
#define POOL_CHUNK 64

// Pass 1: bucket histogram (LDS-privatized) + row-degree (fire-and-forget atomics)
__global__ __launch_bounds__(1024) void k_hist(const int* __restrict__ row,
                                               const int* __restrict__ col,
                                               int* __restrict__ deg,
                                               int* __restrict__ bhist) {
    __shared__ int lh[NBUCK];
    for (int i = threadIdx.x; i < NBUCK; i += blockDim.x) lh[i] = 0;
    __syncthreads();
    int stride = gridDim.x * blockDim.x;
    for (int e = blockIdx.x * blockDim.x + threadIdx.x; e < N_EDGES; e += stride) {
        atomicAdd(&deg[row[e]], 1);
        atomicAdd(&lh[(unsigned)col[e] / CPB], 1);
    }
    __syncthreads();
    for (int i = threadIdx.x; i < NBUCK; i += blockDim.x)
        if (lh[i]) atomicAdd(&bhist[i], lh[i]);
}

// Pass 2: exclusive scan of 16-padded bucket counts -> 64B-aligned bucket bases
__global__ __launch_bounds__(256) void k_scan(const int* __restrict__ bhist,
                                              int* __restrict__ bbase,
                                              int* __restrict__ bfill) {
    __shared__ int sd[NBUCK];
    int t = threadIdx.x;
    int v = (bhist[t] + 15) & ~15;   // pad to 16 records (64B) for aligned flushes
    sd[t] = v;
    __syncthreads();
    for (int off = 1; off < NBUCK; off <<= 1) {
        int a = (t >= off) ? sd[t - off] : 0;
        __syncthreads();
        sd[t] += a;
        __syncthreads();
    }
    int excl = sd[t] - v;
    bbase[t] = excl;
    bfill[t] = excl;
    if (t == NBUCK - 1) bbase[NBUCK] = sd[t];
}

// Pass 3: bucket-grouping of edges via LDS bins; full 16-rec (64B) line-dense flushes.
// rec = (localcol << 17) | row   (row < 2^17, localcol < 391 < 2^9)
__global__ __launch_bounds__(FILL_T) void k_binfill(const int* __restrict__ row,
                                                    const int* __restrict__ col,
                                                    int* __restrict__ bfill,
                                                    unsigned* __restrict__ recs) {
    __shared__ int bincnt[NBUCK];
    __shared__ unsigned binrec[NBUCK * BIN_CAP];   // 32 KiB
    for (int i = threadIdx.x; i < NBUCK; i += FILL_T) bincnt[i] = 0;
    __syncthreads();
    int wid = threadIdx.x >> 6, lane = threadIdx.x & 63;
    for (int rd = 0; rd < ROUNDS; ++rd) {
        int e = rd * (G_FILL * FILL_T) + blockIdx.x * FILL_T + threadIdx.x;
        if (e < N_EDGES) {
            unsigned c = (unsigned)col[e];
            unsigned r = (unsigned)row[e];
            unsigned b = c / CPB;
            unsigned rec = ((c - b * CPB) << 17) | r;
            int idx = atomicAdd(&bincnt[b], 1);
            if (idx < BIN_CAP) {
                binrec[b * BIN_CAP + idx] = rec;
            } else {
                atomicSub(&bincnt[b], 1);               // straggler (statistically ~never)
                int slot = atomicAdd(&bfill[b], 1);
                recs[slot] = rec;
            }
        }
        __syncthreads();
        // flush phase: wave w owns bins w, w+16, ...
        for (int b = wid; b < NBUCK; b += FILL_T / 64) {
            int c = bincnt[b];
            if (c >= 16) {
                int slot = 0;
                if (lane == 0) slot = atomicAdd(&bfill[b], 16);
                slot = __shfl(slot, 0);
                if (lane < 16) recs[slot + lane] = binrec[b * BIN_CAP + lane];
                int rem = c - 16;
                unsigned m = 0;
                if (lane < rem) m = binrec[b * BIN_CAP + 16 + lane];
                if (lane < rem) binrec[b * BIN_CAP + lane] = m;
                if (lane == 0) bincnt[b] = rem;
            }
        }
        __syncthreads();
    }
    // drain residual bins (partial stores, once)
    for (int b = wid; b < NBUCK; b += FILL_T / 64) {
        int c = bincnt[b];
        if (c > 0) {
            int slot = 0;
            if (lane == 0) slot = atomicAdd(&bfill[b], c);
            slot = __shfl(slot, 0);
            if (lane < c) recs[slot + lane] = binrec[b * BIN_CAP + lane];
        }
    }
}

__global__ __launch_bounds__(256) void k_dinv(const int* __restrict__ deg,
                                              float* __restrict__ dinv) {
    int i = blockIdx.x * blockDim.x + threadIdx.x;
    if (i >= N_NODES) return;
    int d = deg[i];
    dinv[i] = d > 0 ? rsqrtf((float)d) : 0.0f;
}

// conv1 node transform: center = x@W1+b1, xj = x@W2   (3 -> 16)
__global__ __launch_bounds__(256) void k_node1(const float* __restrict__ x,
                                               const float* __restrict__ W1,
                                               const float* __restrict__ b1,
                                               const float* __restrict__ W2,
                                               float* __restrict__ center,
                                               float* __restrict__ xj) {
    int t = blockIdx.x * blockDim.x + threadIdx.x;
    if (t >= N_NODES * F) return;
    int n = t >> 4, k = t & 15;
    float x0 = x[n * 3 + 0], x1 = x[n * 3 + 1], x2 = x[n * 3 + 2];
    center[t] = b1[k] + x0 * W1[0 * F + k] + x1 * W1[1 * F + k] + x2 * W1[2 * F + k];
    xj[t]     =         x0 * W2[0 * F + k] + x1 * W2[1 * F + k] + x2 * W2[2 * F + k];
}

// Per-bucket LDS-tile gather: s[n,:] = dinv[n]/max(indeg,1) * sum_{e:col=n} dinv[r]*xj[r,:]
__global__ __launch_bounds__(1024) void k_gather(const unsigned* __restrict__ recs,
                                                 const int* __restrict__ bbase,
                                                 const int* __restrict__ bhist,
                                                 const float* __restrict__ dinv,
                                                 const float* __restrict__ xj,
                                                 float* __restrict__ s_out) {
    __shared__ float st[CPB * 17];   // stride 17 floats -> bank spread
    __shared__ int ct[CPB];
    int b = blockIdx.x;
    for (int i = threadIdx.x; i < CPB * 17; i += 1024) st[i] = 0.0f;
    for (int i = threadIdx.x; i < CPB; i += 1024) ct[i] = 0;
    __syncthreads();
    int beg = bbase[b], end = beg + bhist[b];
    for (int j = beg + threadIdx.x; j < end; j += 1024) {
        unsigned rec = recs[j];
        int r  = rec & 0x1FFFF;
        int lc = rec >> 17;
        float w = dinv[r];
        const float4* x4 = (const float4*)(xj + r * F);
        float* dst = &st[lc * 17];
        atomicAdd(&ct[lc], 1);
#pragma unroll
        for (int q = 0; q < 4; ++q) {
            float4 v = x4[q];
            atomicAdd(&dst[q * 4 + 0], w * v.x);
            atomicAdd(&dst[q * 4 + 1], w * v.y);
            atomicAdd(&dst[q * 4 + 2], w * v.z);
            atomicAdd(&dst[q * 4 + 3], w * v.w);
        }
    }
    __syncthreads();
    for (int i = threadIdx.x; i < CPB * 4; i += 1024) {
        int lc = i >> 2, q = i & 3;
        int n = b * CPB + lc;
        if (n >= N_NODES) continue;
        int c = ct[lc];
        float scale = dinv[n] / (float)(c > 1 ? c : 1);
        float4 o;
        o.x = st[lc * 17 + q * 4 + 0] * scale;
        o.y = st[lc * 17 + q * 4 + 1] * scale;
        o.z = st[lc * 17 + q * 4 + 2] * scale;
        o.w = st[lc * 17 + q * 4 + 3] * scale;
        ((float4*)(s_out + n * F))[q] = o;
    }
}

// finalize conv1 (relu(center + s)) then conv2 node transform (16->16)
__global__ __launch_bounds__(256) void k_node2(float* center_io, const float* __restrict__ s,
                                               const float* __restrict__ W1,
                                               const float* __restrict__ b1,
                                               const float* __restrict__ W2,
                                               float* xj_io) {
    int n = blockIdx.x * blockDim.x + threadIdx.x;
    if (n >= N_NODES) return;
    float h[F];
#pragma unroll
    for (int k = 0; k < F; ++k) {
        float v = center_io[n * F + k] + s[n * F + k];
        h[k] = v > 0.0f ? v : 0.0f;
    }
#pragma unroll
    for (int k = 0; k < F; ++k) {
        float c2 = b1[k];
        float x2 = 0.0f;
#pragma unroll
        for (int i = 0; i < F; ++i) {
            c2 += h[i] * W1[i * F + k];
            x2 += h[i] * W2[i * F + k];
        }
        center_io[n * F + k] = c2;
        xj_io[n * F + k] = x2;
    }
}

// run-length pooling over sorted batch
__global__ __launch_bounds__(256) void k_pool(const float* __restrict__ center,
                                              const float* __restrict__ s,
                                              const int* __restrict__ batch,
                                              float* __restrict__ gpool,
                                              int* __restrict__ gcnt) {
    int t = blockIdx.x * blockDim.x + threadIdx.x;
    int gid = t >> 4, k = t & 15;
    int n0 = gid * POOL_CHUNK;
    if (n0 >= N_NODES) return;
    int n1 = n0 + POOL_CHUNK; if (n1 > N_NODES) n1 = N_NODES;
    int bcur = batch[n0];
    float acc = 0.0f; int run = 0;
    for (int n = n0; n < n1; ++n) {
        int b = batch[n];
        if (b != bcur) {
            atomicAdd(&gpool[bcur * F + k], acc);
            if (k == 0) atomicAdd(&gcnt[bcur], run);
            acc = 0.0f; run = 0; bcur = b;
        }
        float h = center[n * F + k] + s[n * F + k];
        acc += h > 0.0f ? h : 0.0f;
        ++run;
    }
    atomicAdd(&gpool[bcur * F + k], acc);
    if (k == 0) atomicAdd(&gcnt[bcur], run);
}

__global__ __launch_bounds__(64) void k_mlp(const float* __restrict__ gpool,
                                            const int* __restrict__ gcnt,
                                            const float* __restrict__ l1W,
                                            const float* __restrict__ l1b,
                                            const float* __restrict__ l2W,
                                            const float* __restrict__ l2b,
                                            float* __restrict__ out) {
    int g = threadIdx.x;
    if (g >= N_GRAPHS) return;
    int c = gcnt[g];
    float ic = 1.0f / (float)(c > 1 ? c : 1);
    float v[F], h[F];
#pragma unroll
    for (int k = 0; k < F; ++k) v[k] = gpool[g * F + k] * ic;
#pragma unroll
    for (int k = 0; k < F; ++k) {
        float a = l1b[k];
#pragma unroll
        for (int i = 0; i < F; ++i) a += v[i] * l1W[i * F + k];
        h[k] = a > 0.0f ? a : 0.0f;
    }
#pragma unroll
    for (int j = 0; j < 2; ++j) {
        float a = l2b[j];
#pragma unroll
        for (int i = 0; i < F; ++i) a += h[i] * l2W[i * 2 + j];
        out[g * 2 + j] = a;
    }
}

extern "C" void kernel_launch(void* const* d_in, const int* in_sizes, int n_in,
                              void* d_out, int out_size, void* d_ws, size_t ws_size,
                              hipStream_t stream) {
    const float* x     = (const float*)d_in[0];
    const int*   ei    = (const int*)d_in[1];
    const int*   row   = ei;
    const int*   col   = ei + N_EDGES;
    const int*   batch = (const int*)d_in[2];
    const float* c1W1  = (const float*)d_in[3];
    const float* c1b1  = (const float*)d_in[4];
    const float* c1W2  = (const float*)d_in[5];
    const float* c2W1  = (const float*)d_in[6];
    const float* c2b1  = (const float*)d_in[7];
    const float* c2W2  = (const float*)d_in[8];
    const float* l1W   = (const float*)d_in[9];
    const float* l1b   = (const float*)d_in[10];
    const float* l2W   = (const float*)d_in[11];
    const float* l2b   = (const float*)d_in[12];
    float* out = (float*)d_out;

    char* p = (char*)d_ws;
    auto alloc = [&p](size_t bytes) -> void* {
        void* r = (void*)p;
        p += (bytes + 255) & ~(size_t)255;
        return r;
    };
    int*      deg    = (int*)     alloc(N_NODES * 4);
    float*    dinv   = (float*)   alloc(N_NODES * 4);
    float*    center = (float*)   alloc((size_t)N_NODES * F * 4);
    float*    xj     = (float*)   alloc((size_t)N_NODES * F * 4);
    float*    s      = (float*)   alloc((size_t)N_NODES * F * 4);
    float*    gpool  = (float*)   alloc(N_GRAPHS * F * 4);
    int*      gcnt   = (int*)     alloc(N_GRAPHS * 4);
    int*      bhist  = (int*)     alloc(NBUCK * 4);
    int*      bbase  = (int*)     alloc((NBUCK + 1) * 4);
    int*      bfill  = (int*)     alloc(NBUCK * 4);
    unsigned* recs   = (unsigned*)alloc(((size_t)N_EDGES + NBUCK * 16) * 4);

    hipMemsetAsync(deg, 0, N_NODES * 4, stream);
    hipMemsetAsync(bhist, 0, NBUCK * 4, stream);
    hipMemsetAsync(gpool, 0, N_GRAPHS * F * 4, stream);
    hipMemsetAsync(gcnt, 0, N_GRAPHS * 4, stream);

    k_hist<<<256, 1024, 0, stream>>>(row, col, deg, bhist);
    k_scan<<<1, 256, 0, stream>>>(bhist, bbase, bfill);
    k_binfill<<<G_FILL, FILL_T, 0, stream>>>(row, col, bfill, recs);
    k_dinv<<<(N_NODES + 255) / 256, 256, 0, stream>>>(deg, dinv);
    k_node1<<<(N_NODES * F + 255) / 256, 256, 0, stream>>>(x, c1W1, c1b1, c1W2, center, xj);

    k_gather<<<NBUCK, 1024, 0, stream>>>(recs, bbase, bhist, dinv, xj, s);
    k_node2<<<(N_NODES + 255) / 256, 256, 0, stream>>>(center, s, c2W1, c2b1, c2W2, xj);
    k_gather<<<NBUCK, 1024, 0, stream>>>(recs, bbase, bhist, dinv, xj, s);

    k_pool<<<((N_NODES + POOL_CHUNK - 1) / POOL_CHUNK * 16 + 255) / 256, 256, 0, stream>>>(
        center, s, batch, gpool, gcnt);
    k_mlp<<<1, 64, 0, stream>>>(gpool, gcnt, l1W, l1b, l2W, l2b, out);
}

// Round 4
// 759.876 us; speedup vs baseline: 1.3495x; 1.3495x over previous
//
#include <hip/hip_runtime.h>

#define N_NODES 100000
#define N_EDGES 3200000
#define N_GRAPHS 64
#define F 16

#define NBUCK 256
#define CPB 391                 // cols per bucket: 256*391 = 100096 >= N_NODES
#define NBLK 512                // sort blocks
#define EPB ((N_EDGES + NBLK - 1) / NBLK)   // 6250 edges per block
#define POOL_CHUNK 64

// Pass 1: per-block bucket histogram (LDS) -> cntmat[bucket][block]; deg atomics ride along
__global__ __launch_bounds__(256) void k_hist2(const int* __restrict__ row,
                                               const int* __restrict__ col,
                                               int* __restrict__ deg,
                                               int* __restrict__ cntmat) {
    __shared__ int lh[NBUCK];
    for (int i = threadIdx.x; i < NBUCK; i += 256) lh[i] = 0;
    __syncthreads();
    int beg = blockIdx.x * EPB;
    int end = beg + EPB; if (end > N_EDGES) end = N_EDGES;
    for (int e = beg + threadIdx.x; e < end; e += 256) {
        atomicAdd(&deg[row[e]], 1);
        atomicAdd(&lh[(unsigned)col[e] / CPB], 1);
    }
    __syncthreads();
    for (int i = threadIdx.x; i < NBUCK; i += 256)
        cntmat[i * NBLK + blockIdx.x] = lh[i];
}

// Pass 2: per-bucket exclusive scan across blocks (512 values, 256 threads x 2)
__global__ __launch_bounds__(256) void k_colscan(int* __restrict__ cntmat,
                                                 int* __restrict__ bhist) {
    __shared__ int sd[256];
    int b = blockIdx.x, t = threadIdx.x;
    int a0 = cntmat[b * NBLK + 2 * t];
    int a1 = cntmat[b * NBLK + 2 * t + 1];
    int ps = a0 + a1;
    sd[t] = ps;
    __syncthreads();
    for (int off = 1; off < 256; off <<= 1) {
        int v = (t >= off) ? sd[t - off] : 0;
        __syncthreads();
        sd[t] += v;
        __syncthreads();
    }
    int excl = sd[t] - ps;
    cntmat[b * NBLK + 2 * t] = excl;
    cntmat[b * NBLK + 2 * t + 1] = excl + a0;
    if (t == 255) bhist[b] = sd[255];
}

// Pass 3: exclusive scan of 16-padded bucket totals -> 64B-aligned bases
__global__ __launch_bounds__(256) void k_bscan(const int* __restrict__ bhist,
                                               int* __restrict__ bbase) {
    __shared__ int sd[NBUCK];
    int t = threadIdx.x;
    int v = (bhist[t] + 15) & ~15;
    sd[t] = v;
    __syncthreads();
    for (int off = 1; off < NBUCK; off <<= 1) {
        int a = (t >= off) ? sd[t - off] : 0;
        __syncthreads();
        sd[t] += a;
        __syncthreads();
    }
    bbase[t] = sd[t] - v;
}

// Pass 4: deterministic scatter into bucket-grouped recs; dense per-(block,bucket) segments
// rec = (localcol << 17) | row
__global__ __launch_bounds__(256) void k_fill2(const int* __restrict__ row,
                                               const int* __restrict__ col,
                                               const int* __restrict__ cntmat,
                                               const int* __restrict__ bbase,
                                               unsigned* __restrict__ recs) {
    __shared__ int ptr[NBUCK];
    for (int i = threadIdx.x; i < NBUCK; i += 256)
        ptr[i] = bbase[i] + cntmat[i * NBLK + blockIdx.x];
    __syncthreads();
    int beg = blockIdx.x * EPB;
    int end = beg + EPB; if (end > N_EDGES) end = N_EDGES;
    for (int e = beg + threadIdx.x; e < end; e += 256) {
        unsigned c = (unsigned)col[e];
        unsigned r = (unsigned)row[e];
        unsigned b = c / CPB;
        int slot = atomicAdd(&ptr[b], 1);
        recs[slot] = ((c - b * CPB) << 17) | r;
    }
}

__global__ __launch_bounds__(256) void k_dinv(const int* __restrict__ deg,
                                              float* __restrict__ dinv) {
    int i = blockIdx.x * blockDim.x + threadIdx.x;
    if (i >= N_NODES) return;
    int d = deg[i];
    dinv[i] = d > 0 ? rsqrtf((float)d) : 0.0f;
}

// conv1 node transform: center = x@W1+b1, xj = x@W2   (3 -> 16)
__global__ __launch_bounds__(256) void k_node1(const float* __restrict__ x,
                                               const float* __restrict__ W1,
                                               const float* __restrict__ b1,
                                               const float* __restrict__ W2,
                                               float* __restrict__ center,
                                               float* __restrict__ xj) {
    int t = blockIdx.x * blockDim.x + threadIdx.x;
    if (t >= N_NODES * F) return;
    int n = t >> 4, k = t & 15;
    float x0 = x[n * 3 + 0], x1 = x[n * 3 + 1], x2 = x[n * 3 + 2];
    center[t] = b1[k] + x0 * W1[0 * F + k] + x1 * W1[1 * F + k] + x2 * W1[2 * F + k];
    xj[t]     =         x0 * W2[0 * F + k] + x1 * W2[1 * F + k] + x2 * W2[2 * F + k];
}

// Per-bucket LDS-tile gather: s[n,:] = dinv[n]/max(indeg,1) * sum_{e:col=n} dinv[r]*xj[r,:]
__global__ __launch_bounds__(1024) void k_gather(const unsigned* __restrict__ recs,
                                                 const int* __restrict__ bbase,
                                                 const int* __restrict__ bhist,
                                                 const float* __restrict__ dinv,
                                                 const float* __restrict__ xj,
                                                 float* __restrict__ s_out) {
    __shared__ float st[CPB * 17];   // stride 17 floats -> bank spread
    __shared__ int ct[CPB];
    int b = blockIdx.x;
    for (int i = threadIdx.x; i < CPB * 17; i += 1024) st[i] = 0.0f;
    for (int i = threadIdx.x; i < CPB; i += 1024) ct[i] = 0;
    __syncthreads();
    int beg = bbase[b], end = beg + bhist[b];
    for (int j = beg + threadIdx.x; j < end; j += 1024) {
        unsigned rec = recs[j];
        int r  = rec & 0x1FFFF;
        int lc = rec >> 17;
        float w = dinv[r];
        const float4* x4 = (const float4*)(xj + r * F);
        float* dst = &st[lc * 17];
        atomicAdd(&ct[lc], 1);
#pragma unroll
        for (int q = 0; q < 4; ++q) {
            float4 v = x4[q];
            atomicAdd(&dst[q * 4 + 0], w * v.x);
            atomicAdd(&dst[q * 4 + 1], w * v.y);
            atomicAdd(&dst[q * 4 + 2], w * v.z);
            atomicAdd(&dst[q * 4 + 3], w * v.w);
        }
    }
    __syncthreads();
    for (int i = threadIdx.x; i < CPB * 4; i += 1024) {
        int lc = i >> 2, q = i & 3;
        int n = b * CPB + lc;
        if (n >= N_NODES) continue;
        int c = ct[lc];
        float scale = dinv[n] / (float)(c > 1 ? c : 1);
        float4 o;
        o.x = st[lc * 17 + q * 4 + 0] * scale;
        o.y = st[lc * 17 + q * 4 + 1] * scale;
        o.z = st[lc * 17 + q * 4 + 2] * scale;
        o.w = st[lc * 17 + q * 4 + 3] * scale;
        ((float4*)(s_out + n * F))[q] = o;
    }
}

// finalize conv1 (relu(center + s)) then conv2 node transform (16->16)
__global__ __launch_bounds__(256) void k_node2(float* center_io, const float* __restrict__ s,
                                               const float* __restrict__ W1,
                                               const float* __restrict__ b1,
                                               const float* __restrict__ W2,
                                               float* xj_io) {
    int n = blockIdx.x * blockDim.x + threadIdx.x;
    if (n >= N_NODES) return;
    float h[F];
#pragma unroll
    for (int k = 0; k < F; ++k) {
        float v = center_io[n * F + k] + s[n * F + k];
        h[k] = v > 0.0f ? v : 0.0f;
    }
#pragma unroll
    for (int k = 0; k < F; ++k) {
        float c2 = b1[k];
        float x2 = 0.0f;
#pragma unroll
        for (int i = 0; i < F; ++i) {
            c2 += h[i] * W1[i * F + k];
            x2 += h[i] * W2[i * F + k];
        }
        center_io[n * F + k] = c2;
        xj_io[n * F + k] = x2;
    }
}

// run-length pooling over sorted batch
__global__ __launch_bounds__(256) void k_pool(const float* __restrict__ center,
                                              const float* __restrict__ s,
                                              const int* __restrict__ batch,
                                              float* __restrict__ gpool,
                                              int* __restrict__ gcnt) {
    int t = blockIdx.x * blockDim.x + threadIdx.x;
    int gid = t >> 4, k = t & 15;
    int n0 = gid * POOL_CHUNK;
    if (n0 >= N_NODES) return;
    int n1 = n0 + POOL_CHUNK; if (n1 > N_NODES) n1 = N_NODES;
    int bcur = batch[n0];
    float acc = 0.0f; int run = 0;
    for (int n = n0; n < n1; ++n) {
        int b = batch[n];
        if (b != bcur) {
            atomicAdd(&gpool[bcur * F + k], acc);
            if (k == 0) atomicAdd(&gcnt[bcur], run);
            acc = 0.0f; run = 0; bcur = b;
        }
        float h = center[n * F + k] + s[n * F + k];
        acc += h > 0.0f ? h : 0.0f;
        ++run;
    }
    atomicAdd(&gpool[bcur * F + k], acc);
    if (k == 0) atomicAdd(&gcnt[bcur], run);
}

__global__ __launch_bounds__(64) void k_mlp(const float* __restrict__ gpool,
                                            const int* __restrict__ gcnt,
                                            const float* __restrict__ l1W,
                                            const float* __restrict__ l1b,
                                            const float* __restrict__ l2W,
                                            const float* __restrict__ l2b,
                                            float* __restrict__ out) {
    int g = threadIdx.x;
    if (g >= N_GRAPHS) return;
    int c = gcnt[g];
    float ic = 1.0f / (float)(c > 1 ? c : 1);
    float v[F], h[F];
#pragma unroll
    for (int k = 0; k < F; ++k) v[k] = gpool[g * F + k] * ic;
#pragma unroll
    for (int k = 0; k < F; ++k) {
        float a = l1b[k];
#pragma unroll
        for (int i = 0; i < F; ++i) a += v[i] * l1W[i * F + k];
        h[k] = a > 0.0f ? a : 0.0f;
    }
#pragma unroll
    for (int j = 0; j < 2; ++j) {
        float a = l2b[j];
#pragma unroll
        for (int i = 0; i < F; ++i) a += h[i] * l2W[i * 2 + j];
        out[g * 2 + j] = a;
    }
}

extern "C" void kernel_launch(void* const* d_in, const int* in_sizes, int n_in,
                              void* d_out, int out_size, void* d_ws, size_t ws_size,
                              hipStream_t stream) {
    const float* x     = (const float*)d_in[0];
    const int*   ei    = (const int*)d_in[1];
    const int*   row   = ei;
    const int*   col   = ei + N_EDGES;
    const int*   batch = (const int*)d_in[2];
    const float* c1W1  = (const float*)d_in[3];
    const float* c1b1  = (const float*)d_in[4];
    const float* c1W2  = (const float*)d_in[5];
    const float* c2W1  = (const float*)d_in[6];
    const float* c2b1  = (const float*)d_in[7];
    const float* c2W2  = (const float*)d_in[8];
    const float* l1W   = (const float*)d_in[9];
    const float* l1b   = (const float*)d_in[10];
    const float* l2W   = (const float*)d_in[11];
    const float* l2b   = (const float*)d_in[12];
    float* out = (float*)d_out;

    char* p = (char*)d_ws;
    auto alloc = [&p](size_t bytes) -> void* {
        void* r = (void*)p;
        p += (bytes + 255) & ~(size_t)255;
        return r;
    };
    int*      deg    = (int*)     alloc(N_NODES * 4);
    float*    dinv   = (float*)   alloc(N_NODES * 4);
    float*    center = (float*)   alloc((size_t)N_NODES * F * 4);
    float*    xj     = (float*)   alloc((size_t)N_NODES * F * 4);
    float*    s      = (float*)   alloc((size_t)N_NODES * F * 4);
    float*    gpool  = (float*)   alloc(N_GRAPHS * F * 4);
    int*      gcnt   = (int*)     alloc(N_GRAPHS * 4);
    int*      bhist  = (int*)     alloc(NBUCK * 4);
    int*      bbase  = (int*)     alloc((NBUCK + 1) * 4);
    int*      cntmat = (int*)     alloc((size_t)NBUCK * NBLK * 4);
    unsigned* recs   = (unsigned*)alloc(((size_t)N_EDGES + NBUCK * 16) * 4);

    hipMemsetAsync(deg, 0, N_NODES * 4, stream);
    hipMemsetAsync(gpool, 0, N_GRAPHS * F * 4, stream);
    hipMemsetAsync(gcnt, 0, N_GRAPHS * 4, stream);

    k_hist2<<<NBLK, 256, 0, stream>>>(row, col, deg, cntmat);
    k_colscan<<<NBUCK, 256, 0, stream>>>(cntmat, bhist);
    k_bscan<<<1, 256, 0, stream>>>(bhist, bbase);
    k_fill2<<<NBLK, 256, 0, stream>>>(row, col, cntmat, bbase, recs);
    k_dinv<<<(N_NODES + 255) / 256, 256, 0, stream>>>(deg, dinv);
    k_node1<<<(N_NODES * F + 255) / 256, 256, 0, stream>>>(x, c1W1, c1b1, c1W2, center, xj);

    k_gather<<<NBUCK, 1024, 0, stream>>>(recs, bbase, bhist, dinv, xj, s);
    k_node2<<<(N_NODES + 255) / 256, 256, 0, stream>>>(center, s, c2W1, c2b1, c2W2, xj);
    k_gather<<<NBUCK, 1024, 0, stream>>>(recs, bbase, bhist, dinv, xj, s);

    k_pool<<<((N_NODES + POOL_CHUNK - 1) / POOL_CHUNK * 16 + 255) / 256, 256, 0, stream>>>(
        center, s, batch, gpool, gcnt);
    k_mlp<<<1, 64, 0, stream>>>(gpool, gcnt, l1W, l1b, l2W, l2b, out);
}